// Round 6
// baseline (45.605 us; speedup 1.0000x reference)
//
#include <hip/hip_runtime.h>

// Problem constants
#define NN 20000
#define SS 400
#define QQ 20
#define QP 60                      // floats per (q,p) row
#define NPAIRS ((NN+1)/2)          // 10000 n-pairs
#define JPB 64                     // n-pairs per block (one per lane)
#define NBLK ((NPAIRS + JPB - 1)/JPB)  // 157
#define JPAD (NBLK*JPB)            // 10048
#define NP2 (JPAD*2)               // 20096 padded n
#define GSPLIT 10                  // s chunks across gridDim.y
#define SB (SS/GSPLIT)             // 40 s per block
#define WAVES 8
#define BLK_B (WAVES*64)           // 512
#define SW (SB/WAVES)              // 5 s per wave

// ws layout (floats); ws is 256 MiB so all tables fit easily
#define WS_H    0                        // heads2 (r2-folded into q0 chunk) [400][60]
#define WS_P    (SS*QP)                  // 24000: pauli pair table [JPAD][60][2]
#define WS_COV  (WS_P + JPAD*QP*2)       // 1229760: partial coverage [GSPLIT][NP2]
#define WS_PART (WS_COV + GSPLIT*NP2)    // per-block term partials
#define CBLK    ((NP2 + 255)/256)        // 79 combine blocks

typedef float v2f __attribute__((ext_vector_type(2)));

__device__ __forceinline__ v2f lo4(float4 f) { v2f r; r.x = f.x; r.y = f.y; return r; }
__device__ __forceinline__ v2f hi4(float4 f) { v2f r; r.x = f.z; r.y = f.w; return r; }

// prep: 1.2M threads — squares+echo outputs, r2-folded heads table,
// and the pauli (n,n+1) pair-interleaved table.
__global__ void prep_kernel(const float* __restrict__ heads_param,
                            const float* __restrict__ ratios_param,
                            const float* __restrict__ pauli,
                            float* __restrict__ out, float* __restrict__ ws) {
    int i = blockIdx.x * blockDim.x + threadIdx.x;
    if (i < NN*QP) {
        int n = i / QP, k = i - n * QP;
        int j = n >> 1, b = n & 1;
        ws[WS_P + j*(QP*2) + k*2 + b] = pauli[i];
    }
    if (i < SS*QP) {
        int s = i / QP, k = i - s * QP;
        float v = heads_param[i];
        float v2 = v * v;
        out[1 + SS + i] = v2;                    // heads output (unscaled)
        float r = ratios_param[s];
        ws[WS_H + i] = (k < 3) ? v2 * (r*r) : v2;  // fold r2 into the q=0 dot
    }
    if (i < SS) {
        float r = ratios_param[i];
        out[1 + i] = r * r;                      // ratios output
    }
}

// One s-step for q-chunk c: 3 broadcast ds_read_b128 of this s's heads chunk,
// 15 packed (v_pk_*) ops covering (1 s, 4 q, 2 n).
#define S_STEP(A, S)                                                    \
    do {                                                                \
        const float4* hf = reinterpret_cast<const float4*>(hw + (S)*QP + c*12); \
        float4 f0 = hf[0], f1 = hf[1], f2 = hf[2];                      \
        v2f d0 = pq0*f0.x + pq1*f0.y  + pq2*f0.z;                       \
        v2f d1 = pq3*f0.w + pq4*f1.x  + pq5*f1.y;                       \
        v2f d2 = pq6*f1.z + pq7*f1.w  + pq8*f2.x;                       \
        v2f d3 = pq9*f2.y + pq10*f2.z + pq11*f2.w;                      \
        A *= (d0*d1)*(d2*d3);                                           \
    } while (0)

__global__ __launch_bounds__(BLK_B) void main_kernel(float* __restrict__ ws) {
    __shared__ float ldsH[SB*QP];        // 40*60*4 = 9.6 KB
    __shared__ v2f   ldsC[WAVES][64];    // 4 KB cross-wave reduce

    const int tid  = threadIdx.x;
    const int wave = __builtin_amdgcn_readfirstlane(tid >> 6);
    const int lane = tid & 63;
    const int g    = blockIdx.y;
    const int j    = blockIdx.x * JPB + lane;     // this lane's n-pair

    // Stage this block's 40 heads rows (r2-folded) into LDS, coalesced
    {
        const float4* src = reinterpret_cast<const float4*>(ws + WS_H + (size_t)g * (SB*QP));
        float4* dst = reinterpret_cast<float4*>(ldsH);
        for (int i = tid; i < SB*QP/4; i += BLK_B) dst[i] = src[i];
    }
    __syncthreads();

    const float4* ppj = reinterpret_cast<const float4*>(ws + WS_P + (size_t)j * (QP*2));
    const float* hw = ldsH + wave * (SW*QP);

    // Per-s partial-product accumulators over the (n,n+1) pair
    v2f a0, a1, a2, a3, a4;
    a0.x = 1.f; a0.y = 1.f; a1 = a0; a2 = a0; a3 = a0; a4 = a0;

    #pragma unroll 1    // keep q-phases serial: 24 pauli floats live at a time
    for (int c = 0; c < 5; ++c) {
        float4 q0 = ppj[c*6+0], q1 = ppj[c*6+1], q2 = ppj[c*6+2];
        float4 q3 = ppj[c*6+3], q4 = ppj[c*6+4], q5 = ppj[c*6+5];
        v2f pq0 = lo4(q0), pq1  = hi4(q0), pq2  = lo4(q1), pq3  = hi4(q1);
        v2f pq4 = lo4(q2), pq5  = hi4(q2), pq6  = lo4(q3), pq7  = hi4(q3);
        v2f pq8 = lo4(q4), pq9  = hi4(q4), pq10 = lo4(q5), pq11 = hi4(q5);
        S_STEP(a0, 0);
        S_STEP(a1, 1);
        S_STEP(a2, 2);
        S_STEP(a3, 3);
        S_STEP(a4, 4);
    }

    // Sum over this wave's s (r2 already folded in)
    v2f cv = ((a0 + a1) + (a2 + a3)) + a4;
    ldsC[wave][lane] = cv;
    __syncthreads();

    if (wave == 0) {
        v2f t = ldsC[0][lane];
        #pragma unroll
        for (int w = 1; w < WAVES; ++w) t += ldsC[w][lane];
        *reinterpret_cast<v2f*>(ws + WS_COV + (size_t)g * NP2 + 2*j) = t;
    }
}

__global__ void combine_kernel(const float* __restrict__ wsc,
                               const float* __restrict__ coeff,
                               float* __restrict__ ws) {
    __shared__ float red[4];
    const int tid = threadIdx.x;
    const int n = blockIdx.x * 256 + tid;
    float term = 0.f;
    if (n < NN) {
        float cov = 0.f;
        #pragma unroll
        for (int g = 0; g < GSPLIT; ++g) cov += wsc[WS_COV + (size_t)g * NP2 + n];
        float c = coeff[n];
        term = (c * c) / cov;
    }
    #pragma unroll
    for (int off = 32; off; off >>= 1) term += __shfl_down(term, off);
    if ((tid & 63) == 0) red[tid >> 6] = term;
    __syncthreads();
    if (tid == 0) ws[WS_PART + blockIdx.x] = red[0] + red[1] + red[2] + red[3];
}

__global__ void final_kernel(const float* __restrict__ ws, float* __restrict__ out) {
    int tid = threadIdx.x;  // 128 threads
    double acc = 0.0;
    for (int i = tid; i < CBLK; i += 128) acc += (double)ws[WS_PART + i];
    #pragma unroll
    for (int off = 32; off; off >>= 1) acc += __shfl_down(acc, off);
    __shared__ double r2[2];
    if ((tid & 63) == 0) r2[tid >> 6] = acc;
    __syncthreads();
    if (tid == 0) out[0] = (float)(r2[0] + r2[1]);
}

extern "C" void kernel_launch(void* const* d_in, const int* in_sizes, int n_in,
                              void* d_out, int out_size, void* d_ws, size_t ws_size,
                              hipStream_t stream) {
    const float* heads_param  = (const float*)d_in[0];   // [S,Q,P]
    const float* ratios_param = (const float*)d_in[1];   // [S]
    const float* pauli        = (const float*)d_in[2];   // [N,Q,P]
    const float* coeff        = (const float*)d_in[3];   // [N]
    float* out = (float*)d_out;
    float* ws  = (float*)d_ws;

    prep_kernel<<<(NN*QP + 255)/256, 256, 0, stream>>>(heads_param, ratios_param, pauli, out, ws);
    main_kernel<<<dim3(NBLK, GSPLIT), BLK_B, 0, stream>>>(ws);
    combine_kernel<<<CBLK, 256, 0, stream>>>(ws, coeff, ws);
    final_kernel<<<1, 128, 0, stream>>>(ws, out);
}

// Round 7
// 34.428 us; speedup vs baseline: 1.3247x; 1.3247x over previous
//
#include <hip/hip_runtime.h>

// Problem constants
#define NN 20000
#define SS 400
#define QP 60                      // floats per (q,p) row
#define NPAIRS 10000               // n-pairs
#define JPB 64                     // n-pairs per block (one per lane)
#define NBLK ((NPAIRS + JPB - 1)/JPB)  // 157
#define JPAD (NBLK*JPB)            // 10048
#define NP2 (JPAD*2)               // 20096 padded n
#define GSPLIT 5                   // s chunks across gridDim.y
#define SB (SS/GSPLIT)             // 80 s per block
#define WAVES 8
#define BLK_B (WAVES*64)           // 512
#define SW (SB/WAVES)              // 10 s per wave
#define PTF4 (JPB*30)              // 1920 float4 per block's pauli tile

// ws layout (floats)
#define WS_H    0                            // heads2 r2-folded [400][60]
#define WS_PT   (SS*QP)                      // 24000: block-transposed pauli [NBLK][30][64] float4
#define WS_COV  (WS_PT + NBLK*PTF4*4)        // partial coverage [GSPLIT][NP2]
#define WS_PART (WS_COV + GSPLIT*NP2)        // per-block term partials
#define CBLK    ((NP2 + 255)/256)            // 79 combine blocks

typedef float v2f __attribute__((ext_vector_type(2)));

__device__ __forceinline__ v2f lo4(float4 f) { v2f r; r.x = f.x; r.y = f.y; return r; }
__device__ __forceinline__ v2f hi4(float4 f) { v2f r; r.x = f.z; r.y = f.w; return r; }

// prep: echo outputs, r2-folded heads table, block-transposed pauli pair table.
__global__ void prep_kernel(const float* __restrict__ heads_param,
                            const float* __restrict__ ratios_param,
                            const float* __restrict__ pauli,
                            float* __restrict__ out, float* __restrict__ ws) {
    int i = blockIdx.x * blockDim.x + threadIdx.x;
    if (i < NBLK*PTF4) {
        int bx   = i / PTF4;
        int r    = i - bx*PTF4;
        int k    = r >> 6;              // 0..29 (qp pair index)
        int lane = r & 63;
        int j    = bx*JPB + lane;       // global n-pair
        float4 v = make_float4(0.f, 0.f, 0.f, 0.f);
        if (j < NPAIRS) {
            const float* p0 = pauli + (size_t)(2*j) * QP;
            v.x = p0[2*k];      v.z = p0[2*k+1];       // n = 2j
            v.y = p0[QP+2*k];   v.w = p0[QP+2*k+1];    // n = 2j+1
        }
        reinterpret_cast<float4*>(ws + WS_PT)[i] = v;  // coalesced write
    }
    if (i < SS*QP) {
        int s = i / QP;
        float h = heads_param[i];
        float h2 = h * h;
        out[1 + SS + i] = h2;                          // heads output (unscaled)
        float rr = ratios_param[s];
        ws[WS_H + i] = ((i - s*QP) < 3) ? h2 * (rr*rr) : h2;  // fold r2 into q=0 dot
    }
    if (i < SS) {
        float rr = ratios_param[i];
        out[1 + i] = rr * rr;                          // ratios output
    }
}

// One s-step for q-chunk c: 3 wave-uniform (s_load) reads of heads chunk,
// 15 packed ops covering (1 s, 4 q, 2 n).
#define S_STEP(A, SI)                                                   \
    do {                                                                \
        const float4* hf = reinterpret_cast<const float4*>(hrow + (SI)*QP + c*12); \
        float4 f0 = hf[0], f1 = hf[1], f2 = hf[2];                      \
        v2f d0 = pq0*f0.x + pq1*f0.y  + pq2*f0.z;                       \
        v2f d1 = pq3*f0.w + pq4*f1.x  + pq5*f1.y;                       \
        v2f d2 = pq6*f1.z + pq7*f1.w  + pq8*f2.x;                       \
        v2f d3 = pq9*f2.y + pq10*f2.z + pq11*f2.w;                      \
        A *= (d0*d1)*(d2*d3);                                           \
    } while (0)

__global__ __launch_bounds__(BLK_B) void main_kernel(
        const float* __restrict__ hws,   // ws + WS_H  (read-only, disjoint)
        const float4* __restrict__ pt,   // ws + WS_PT (read-only, disjoint)
        float* __restrict__ cov) {       // ws + WS_COV (write)
    __shared__ float4 ldsP[PTF4];        // 30 KB block-transposed pauli tile
    __shared__ v2f    ldsC[WAVES][64];   // 4 KB cross-wave reduce

    const int tid  = threadIdx.x;
    const int wave = __builtin_amdgcn_readfirstlane(tid >> 6);
    const int lane = tid & 63;
    const int g    = blockIdx.y;

    // Stage this block's pauli tile: linear copy, coalesced + conflict-free
    {
        const float4* src = pt + (size_t)blockIdx.x * PTF4;
        for (int i = tid; i < PTF4; i += BLK_B) ldsP[i] = src[i];
    }
    __syncthreads();

    // This wave's 10 heads rows (wave-uniform address -> scalar loads)
    const float* hrow = hws + (size_t)(g*SB + wave*SW) * QP;

    v2f one; one.x = 1.f; one.y = 1.f;
    v2f a0=one,a1=one,a2=one,a3=one,a4=one,a5=one,a6=one,a7=one,a8=one,a9=one;

    #pragma unroll 1    // q-phase split: 24 pauli floats live at a time
    for (int c = 0; c < 5; ++c) {
        float4 q0 = ldsP[(c*6+0)*64+lane], q1 = ldsP[(c*6+1)*64+lane];
        float4 q2 = ldsP[(c*6+2)*64+lane], q3 = ldsP[(c*6+3)*64+lane];
        float4 q4 = ldsP[(c*6+4)*64+lane], q5 = ldsP[(c*6+5)*64+lane];
        v2f pq0 = lo4(q0), pq1  = hi4(q0), pq2  = lo4(q1), pq3  = hi4(q1);
        v2f pq4 = lo4(q2), pq5  = hi4(q2), pq6  = lo4(q3), pq7  = hi4(q3);
        v2f pq8 = lo4(q4), pq9  = hi4(q4), pq10 = lo4(q5), pq11 = hi4(q5);
        S_STEP(a0, 0); S_STEP(a1, 1); S_STEP(a2, 2); S_STEP(a3, 3); S_STEP(a4, 4);
        S_STEP(a5, 5); S_STEP(a6, 6); S_STEP(a7, 7); S_STEP(a8, 8); S_STEP(a9, 9);
    }

    // Sum over this wave's s (r2 already folded in)
    v2f cv = (((a0+a1)+(a2+a3)) + ((a4+a5)+(a6+a7))) + (a8+a9);
    ldsC[wave][lane] = cv;
    __syncthreads();

    if (wave == 0) {
        v2f t = ldsC[0][lane];
        #pragma unroll
        for (int w = 1; w < WAVES; ++w) t += ldsC[w][lane];
        const int j = blockIdx.x * JPB + lane;
        *reinterpret_cast<v2f*>(cov + (size_t)g * NP2 + 2*j) = t;
    }
}

__global__ void combine_kernel(const float* __restrict__ wsc,
                               const float* __restrict__ coeff,
                               float* __restrict__ ws) {
    __shared__ float red[4];
    const int tid = threadIdx.x;
    const int n = blockIdx.x * 256 + tid;
    float term = 0.f;
    if (n < NN) {
        float cov = 0.f;
        #pragma unroll
        for (int g = 0; g < GSPLIT; ++g) cov += wsc[WS_COV + (size_t)g * NP2 + n];
        float c = coeff[n];
        term = (c * c) / cov;
    }
    #pragma unroll
    for (int off = 32; off; off >>= 1) term += __shfl_down(term, off);
    if ((tid & 63) == 0) red[tid >> 6] = term;
    __syncthreads();
    if (tid == 0) ws[WS_PART + blockIdx.x] = red[0] + red[1] + red[2] + red[3];
}

__global__ void final_kernel(const float* __restrict__ ws, float* __restrict__ out) {
    int tid = threadIdx.x;  // 128 threads
    double acc = 0.0;
    for (int i = tid; i < CBLK; i += 128) acc += (double)ws[WS_PART + i];
    #pragma unroll
    for (int off = 32; off; off >>= 1) acc += __shfl_down(acc, off);
    __shared__ double r2[2];
    if ((tid & 63) == 0) r2[tid >> 6] = acc;
    __syncthreads();
    if (tid == 0) out[0] = (float)(r2[0] + r2[1]);
}

extern "C" void kernel_launch(void* const* d_in, const int* in_sizes, int n_in,
                              void* d_out, int out_size, void* d_ws, size_t ws_size,
                              hipStream_t stream) {
    const float* heads_param  = (const float*)d_in[0];   // [S,Q,P]
    const float* ratios_param = (const float*)d_in[1];   // [S]
    const float* pauli        = (const float*)d_in[2];   // [N,Q,P]
    const float* coeff        = (const float*)d_in[3];   // [N]
    float* out = (float*)d_out;
    float* ws  = (float*)d_ws;

    prep_kernel<<<(NBLK*PTF4 + 255)/256, 256, 0, stream>>>(heads_param, ratios_param, pauli, out, ws);
    main_kernel<<<dim3(NBLK, GSPLIT), BLK_B, 0, stream>>>(ws + WS_H, (const float4*)(ws + WS_PT), ws + WS_COV);
    combine_kernel<<<CBLK, 256, 0, stream>>>(ws, coeff, ws);
    final_kernel<<<1, 128, 0, stream>>>(ws, out);
}

// Round 8
// 33.046 us; speedup vs baseline: 1.3800x; 1.0418x over previous
//
#include <hip/hip_runtime.h>

// Problem constants
#define NN 20000
#define SS 400
#define QP 60                      // floats per (q,p) row
#define NPAIRS 10000               // n-pairs
#define JPB 64                     // n-pairs per block (one per lane)
#define NBLK ((NPAIRS + JPB - 1)/JPB)  // 157
#define JPAD (NBLK*JPB)            // 10048
#define NP2 (JPAD*2)               // 20096 padded n
#define GSPLIT 5                   // s chunks across gridDim.y
#define SB (SS/GSPLIT)             // 80 s per block
#define WAVES 8
#define BLK_B (WAVES*64)           // 512
#define SW (SB/WAVES)              // 10 s per wave
#define PTF4 (JPB*30)              // 1920 float4 per block's pauli tile
#define PF4TOT (NN*QP/4)           // 300000 float4 in pauli

// ws layout (floats)
#define WS_H    0                            // heads2 r2-folded [400][60]
#define WS_PT   (SS*QP)                      // 24000: block-transposed pauli [NBLK][30][64] float4
#define WS_COV  (WS_PT + NBLK*PTF4*4)        // partial coverage [GSPLIT][NP2]
#define CBLK    ((NP2 + 255)/256)            // 79 combine blocks

typedef float v2f __attribute__((ext_vector_type(2)));

__device__ __forceinline__ v2f lo4(float4 f) { v2f r; r.x = f.x; r.y = f.y; return r; }
__device__ __forceinline__ v2f hi4(float4 f) { v2f r; r.x = f.z; r.y = f.w; return r; }

// prep: 157 blocks x 512. Coalesced LDS-based pauli pair-transpose +
// heads/ratios echo outputs + r2-folded heads table + out[0]=0 for the atomic.
__global__ __launch_bounds__(512) void prep_kernel(
        const float* __restrict__ heads_param,
        const float* __restrict__ ratios_param,
        const float* __restrict__ pauli,
        float* __restrict__ out, float* __restrict__ ws) {
    __shared__ float ldsR[JPB*2*QP];   // 128 rows x 60 floats = 30 KB

    const int tid = threadIdx.x;
    const int bx  = blockIdx.x;

    // 1) Linear, fully-coalesced load of this block's 128 pauli rows
    {
        const float4* src = reinterpret_cast<const float4*>(pauli) + (size_t)bx * PTF4;
        float4* dst = reinterpret_cast<float4*>(ldsR);
        #pragma unroll
        for (int it = 0; it < 4; ++it) {
            int i = tid + it*512;
            if (i < PTF4) {
                int gi = bx*PTF4 + i;
                dst[i] = (gi < PF4TOT) ? src[i] : make_float4(0.f,0.f,0.f,0.f);
            }
        }
    }
    __syncthreads();

    // 2) Pair-interleaved PT tile, coalesced global writes
    {
        float4* pt = reinterpret_cast<float4*>(ws + WS_PT) + (size_t)bx * PTF4;
        #pragma unroll
        for (int it = 0; it < 4; ++it) {
            int i = tid + it*512;
            if (i < PTF4) {
                int k = i >> 6, l = i & 63;
                float4 v;
                v.x = ldsR[(2*l  )*QP + 2*k    ];
                v.y = ldsR[(2*l+1)*QP + 2*k    ];
                v.z = ldsR[(2*l  )*QP + 2*k + 1];
                v.w = ldsR[(2*l+1)*QP + 2*k + 1];
                pt[i] = v;
            }
        }
    }

    // 3) heads / ratios outputs + r2-folded heads table + zero the loss slot
    const int gi = bx*512 + tid;
    if (gi < SS*QP) {
        int s = gi / QP;
        float h = heads_param[gi];
        float h2 = h * h;
        out[1 + SS + gi] = h2;                         // heads output (unscaled)
        float rr = ratios_param[s];
        ws[WS_H + gi] = ((gi - s*QP) < 3) ? h2 * (rr*rr) : h2;  // fold r2 into q=0 dot
    }
    if (gi < SS) {
        float rr = ratios_param[gi];
        out[1 + gi] = rr * rr;                         // ratios output
    }
    if (gi == 0) out[0] = 0.f;                         // atomic accumulator base
}

// One s-step for q-chunk c: 3 wave-uniform (s_load) reads of heads chunk,
// 15 packed ops covering (1 s, 4 q, 2 n).
#define S_STEP(A, SI)                                                   \
    do {                                                                \
        const float4* hf = reinterpret_cast<const float4*>(hrow + (SI)*QP + c*12); \
        float4 f0 = hf[0], f1 = hf[1], f2 = hf[2];                      \
        v2f d0 = pq0*f0.x + pq1*f0.y  + pq2*f0.z;                       \
        v2f d1 = pq3*f0.w + pq4*f1.x  + pq5*f1.y;                       \
        v2f d2 = pq6*f1.z + pq7*f1.w  + pq8*f2.x;                       \
        v2f d3 = pq9*f2.y + pq10*f2.z + pq11*f2.w;                      \
        A *= (d0*d1)*(d2*d3);                                           \
    } while (0)

__global__ __launch_bounds__(BLK_B) void main_kernel(
        const float* __restrict__ hws,   // ws + WS_H  (read-only, disjoint)
        const float4* __restrict__ pt,   // ws + WS_PT (read-only, disjoint)
        float* __restrict__ cov) {       // ws + WS_COV (write)
    __shared__ float4 ldsP[PTF4];        // 30 KB block-transposed pauli tile
    __shared__ v2f    ldsC[WAVES][64];   // 4 KB cross-wave reduce

    const int tid  = threadIdx.x;
    const int wave = __builtin_amdgcn_readfirstlane(tid >> 6);
    const int lane = tid & 63;
    const int g    = blockIdx.y;

    // Stage this block's pauli tile: linear copy, coalesced + conflict-free
    {
        const float4* src = pt + (size_t)blockIdx.x * PTF4;
        for (int i = tid; i < PTF4; i += BLK_B) ldsP[i] = src[i];
    }
    __syncthreads();

    // This wave's 10 heads rows (wave-uniform address -> scalar loads)
    const float* hrow = hws + (size_t)(g*SB + wave*SW) * QP;

    v2f one; one.x = 1.f; one.y = 1.f;
    v2f a0=one,a1=one,a2=one,a3=one,a4=one,a5=one,a6=one,a7=one,a8=one,a9=one;

    #pragma unroll 1    // q-phase split: 24 pauli floats live at a time
    for (int c = 0; c < 5; ++c) {
        float4 q0 = ldsP[(c*6+0)*64+lane], q1 = ldsP[(c*6+1)*64+lane];
        float4 q2 = ldsP[(c*6+2)*64+lane], q3 = ldsP[(c*6+3)*64+lane];
        float4 q4 = ldsP[(c*6+4)*64+lane], q5 = ldsP[(c*6+5)*64+lane];
        v2f pq0 = lo4(q0), pq1  = hi4(q0), pq2  = lo4(q1), pq3  = hi4(q1);
        v2f pq4 = lo4(q2), pq5  = hi4(q2), pq6  = lo4(q3), pq7  = hi4(q3);
        v2f pq8 = lo4(q4), pq9  = hi4(q4), pq10 = lo4(q5), pq11 = hi4(q5);
        S_STEP(a0, 0); S_STEP(a1, 1); S_STEP(a2, 2); S_STEP(a3, 3); S_STEP(a4, 4);
        S_STEP(a5, 5); S_STEP(a6, 6); S_STEP(a7, 7); S_STEP(a8, 8); S_STEP(a9, 9);
    }

    // Sum over this wave's s (r2 already folded in)
    v2f cv = (((a0+a1)+(a2+a3)) + ((a4+a5)+(a6+a7))) + (a8+a9);
    ldsC[wave][lane] = cv;
    __syncthreads();

    if (wave == 0) {
        v2f t = ldsC[0][lane];
        #pragma unroll
        for (int w = 1; w < WAVES; ++w) t += ldsC[w][lane];
        const int j = blockIdx.x * JPB + lane;
        *reinterpret_cast<v2f*>(cov + (size_t)g * NP2 + 2*j) = t;
    }
}

// combine: sums the GSPLIT cov partials, computes c^2/cov, block-reduces,
// one atomicAdd per block into out[0] (zeroed by prep earlier in-stream).
__global__ void combine_kernel(const float* __restrict__ ws,
                               const float* __restrict__ coeff,
                               float* __restrict__ out) {
    __shared__ float red[4];
    const int tid = threadIdx.x;
    const int n = blockIdx.x * 256 + tid;
    float term = 0.f;
    if (n < NN) {
        float cov = 0.f;
        #pragma unroll
        for (int g = 0; g < GSPLIT; ++g) cov += ws[WS_COV + (size_t)g * NP2 + n];
        float c = coeff[n];
        term = (c * c) / cov;
    }
    #pragma unroll
    for (int off = 32; off; off >>= 1) term += __shfl_down(term, off);
    if ((tid & 63) == 0) red[tid >> 6] = term;
    __syncthreads();
    if (tid == 0) atomicAdd(out, red[0] + red[1] + red[2] + red[3]);
}

extern "C" void kernel_launch(void* const* d_in, const int* in_sizes, int n_in,
                              void* d_out, int out_size, void* d_ws, size_t ws_size,
                              hipStream_t stream) {
    const float* heads_param  = (const float*)d_in[0];   // [S,Q,P]
    const float* ratios_param = (const float*)d_in[1];   // [S]
    const float* pauli        = (const float*)d_in[2];   // [N,Q,P]
    const float* coeff        = (const float*)d_in[3];   // [N]
    float* out = (float*)d_out;
    float* ws  = (float*)d_ws;

    prep_kernel<<<NBLK, 512, 0, stream>>>(heads_param, ratios_param, pauli, out, ws);
    main_kernel<<<dim3(NBLK, GSPLIT), BLK_B, 0, stream>>>(ws + WS_H, (const float4*)(ws + WS_PT), ws + WS_COV);
    combine_kernel<<<CBLK, 256, 0, stream>>>(ws, coeff, out);
}